// Round 15
// baseline (538.033 us; speedup 1.0000x reference)
//
#include <hip/hip_runtime.h>
#include <math.h>

#define BB 512
#define NT 128
#define NREL 201
#define NNODE (BB*NT)
#define NEDGE (NNODE*16)

typedef float f32x4 __attribute__((ext_vector_type(4)));
typedef __attribute__((ext_vector_type(8))) short bf16x8;

__device__ __forceinline__ float sigm(float x) { return 1.f/(1.f + __expf(-x)); }

__device__ __forceinline__ unsigned short f2bf(float f) {
  unsigned u; __builtin_memcpy(&u, &f, 4);
  unsigned r = u + 0x7fffu + ((u >> 16) & 1u);   // RNE
  return (unsigned short)(r >> 16);
}

// ---------------------------------------------------------------- k_rel2 : per-row rel chain + XI (201 blocks x 96)
__global__ __launch_bounds__(96) void k_rel2(const float* __restrict__ rel_emb,
                                             const float* __restrict__ W_rel,
                                             const float* __restrict__ pWih,
                                             const float* __restrict__ pbih,
                                             float* __restrict__ r123,
                                             float* __restrict__ XI) {
  __shared__ float ra[32], rb[32];
  int r = blockIdx.x, tid = threadIdx.x;
  if (tid < 32) ra[tid] = rel_emb[r*32 + tid];
  __syncthreads();
  if (tid < 32) {
    float s = 0.f;
    #pragma unroll
    for (int d = 0; d < 32; ++d) s += ra[d]*W_rel[d*32 + tid];
    rb[tid] = s; r123[0*NREL*32 + r*32 + tid] = s;
  }
  __syncthreads();
  if (tid < 32) {
    float s = 0.f;
    #pragma unroll
    for (int d = 0; d < 32; ++d) s += rb[d]*W_rel[1024 + d*32 + tid];
    ra[tid] = s; r123[1*NREL*32 + r*32 + tid] = s;
  }
  __syncthreads();
  if (tid < 32) {
    float s = 0.f;
    #pragma unroll
    for (int d = 0; d < 32; ++d) s += ra[d]*W_rel[2048 + d*32 + tid];
    rb[tid] = s; r123[2*NREL*32 + r*32 + tid] = s;
  }
  __syncthreads();
  float s = pbih[tid];
  #pragma unroll
  for (int d = 0; d < 32; ++d) s += rb[d]*pWih[tid*32 + d];
  XI[r*96 + tid] = s;
}

// ---------------------------------------------------------------- k_wt1 : WT1bt[576][96] bf16 ; WoBt[96][192] bf16 ; bcat f32
__global__ __launch_bounds__(256) void k_wt1(const float* __restrict__ Wih_f,
                                             const float* __restrict__ Wih_b,
                                             const float* __restrict__ bih_f,
                                             const float* __restrict__ bih_b,
                                             const float* __restrict__ Wo_W,
                                             unsigned short* __restrict__ WT1bt,
                                             unsigned short* __restrict__ WoBt,
                                             float* __restrict__ bcat) {
  int i = blockIdx.x*256 + threadIdx.x;
  if (i < 576*96) {
    int j = i / 96;
    float v = (j < 288) ? Wih_f[i] : Wih_b[i - 288*96];
    WT1bt[i] = f2bf(v);
  }
  if (i < 96*192) {
    int j = i / 192, k = i - j*192;
    WoBt[i] = f2bf(Wo_W[k*96 + j]);
  }
  if (i < 576) bcat[i] = (i < 288) ? bih_f[i] : bih_b[i-288];
}

// ---------------------------------------------------------------- sem attention reading LDS rel table
__device__ __forceinline__ void sem_att_l(const float* __restrict__ rl,
                                          const int rels[8], const float tgt[32],
                                          float out[32]) {
  float dots[8]; float mx = -1e30f;
  #pragma unroll
  for (int k = 0; k < 8; ++k) {
    const float4* er = (const float4*)&rl[rels[k]*32];
    float s = 0.f;
    #pragma unroll
    for (int q = 0; q < 8; ++q) {
      float4 v = er[q];
      s += v.x*tgt[4*q+0] + v.y*tgt[4*q+1] + v.z*tgt[4*q+2] + v.w*tgt[4*q+3];
    }
    dots[k] = s; mx = fmaxf(mx, s);
  }
  float den = 0.f;
  #pragma unroll
  for (int k = 0; k < 8; ++k) { float e = __expf(dots[k]-mx); dots[k] = e; den += e; }
  float inv = 1.f/den;
  #pragma unroll
  for (int d = 0; d < 32; ++d) out[d] = 0.f;
  #pragma unroll
  for (int k = 0; k < 8; ++k) {
    const float4* er = (const float4*)&rl[rels[k]*32];
    float a = dots[k]*inv;
    #pragma unroll
    for (int q = 0; q < 8; ++q) {
      float4 v = er[q];
      out[4*q+0] += a*v.x; out[4*q+1] += a*v.y; out[4*q+2] += a*v.z; out[4*q+3] += a*v.w;
    }
  }
}

// ---------------------------------------------------------------- k_gnn3 : sem + 3 GNN layers fused, CSR gather
__global__ __launch_bounds__(512) void k_gnn3(
    const float* __restrict__ feat, const int* __restrict__ out_rels,
    const int* __restrict__ in_rels, const int* __restrict__ r_label_node,
    const float* __restrict__ w2e_W, const float* __restrict__ w2e_b,
    const float* __restrict__ rel_emb, const float* __restrict__ r123,
    const int* __restrict__ src, const int* __restrict__ dst, const int* __restrict__ etype,
    const float* __restrict__ W_msg, const float* __restrict__ W_self,
    const float* __restrict__ b_gnn,
    float* __restrict__ AT, float* __restrict__ ghid0) {
  __shared__ __align__(16) float hl[NT*36];
  __shared__ __align__(16) float hnew[NT*33];
  __shared__ __align__(16) float rl[NREL*32];
  __shared__ unsigned short eidx[2048];
  __shared__ float scratch[16][32];
  __shared__ int cnt[128], fill[128], scanv[128], rowstart[129];
  int g = blockIdx.x;
  int tid = threadIdx.x;
  int d = tid & 31, grp = tid >> 5;

  // rl <- rel_emb (used by sem AND layer 0)
  for (int i = tid; i < NREL*32; i += 512) rl[i] = rel_emb[i];
  if (tid < 128) { cnt[tid] = 0; fill[tid] = 0; }
  __syncthreads();
  for (int i = tid; i < 2048; i += 512)
    atomicAdd(&cnt[dst[g*2048 + i] - g*NT], 1);
  __syncthreads();
  if (tid < 128) scanv[tid] = cnt[tid];
  __syncthreads();
  #pragma unroll
  for (int off = 1; off < 128; off <<= 1) {
    int v = 0;
    if (tid < 128 && tid >= off) v = scanv[tid - off];
    __syncthreads();
    if (tid < 128) scanv[tid] += v;
    __syncthreads();
  }
  if (tid < 128) { rowstart[tid+1] = scanv[tid]; if (tid == 0) rowstart[0] = 0; }
  __syncthreads();
  for (int i = tid; i < 2048; i += 512) {
    int e = g*2048 + i;
    int dl = dst[e] - g*NT;
    int slot = rowstart[dl] + atomicAdd(&fill[dl], 1);
    eidx[slot] = (unsigned short)(((src[e] - g*NT) << 8) | etype[e]);
  }
  // sem: threads 0..127 compute their node's h0 into hl (reads rl from LDS)
  if (tid < 128) {
    int n = g*NT + tid;
    float tgt[32];
    {
      const float4* tr = (const float4*)&rl[r_label_node[n]*32];
      #pragma unroll
      for (int q = 0; q < 8; ++q) {
        float4 v = tr[q];
        tgt[4*q+0]=v.x; tgt[4*q+1]=v.y; tgt[4*q+2]=v.z; tgt[4*q+3]=v.w;
      }
    }
    int ro[8], ri[8];
    #pragma unroll
    for (int k = 0; k < 8; ++k) { ro[k] = out_rels[n*8+k]; ri[k] = in_rels[n*8+k]; }
    float osem[32], isem[32];
    sem_att_l(rl, ro, tgt, osem);
    sem_att_l(rl, ri, tgt, isem);
    const float4* fr = (const float4*)(feat + (size_t)n*16);
    #pragma unroll
    for (int q = 0; q < 4; ++q) {
      float4 v = fr[q];
      hl[tid*36 + 4*q+0] = v.x; hl[tid*36 + 4*q+1] = v.y;
      hl[tid*36 + 4*q+2] = v.z; hl[tid*36 + 4*q+3] = v.w;
    }
    #pragma unroll
    for (int j = 0; j < 16; ++j) {
      float s = w2e_b[j];
      #pragma unroll
      for (int dd = 0; dd < 32; ++dd) s += osem[dd]*w2e_W[dd*16+j] + isem[dd]*w2e_W[(32+dd)*16+j];
      hl[tid*36 + 16 + j] = sigm(s);
    }
  }

  for (int l = 0; l < 3; ++l) {
    if (l > 0) {
      const float* rsrc = r123 + (size_t)(l-1)*NREL*32;
      for (int i = tid; i < NREL*32; i += 512) rl[i] = rsrc[i];
    }
    float wm[32], ws[32];
    #pragma unroll
    for (int dd = 0; dd < 32; ++dd) {
      wm[dd] = W_msg[l*1024 + dd*32 + d];
      ws[dd] = W_self[l*1024 + dd*32 + d];
    }
    float bj = b_gnn[l*32 + d];
    __syncthreads();                       // rl + hl + eidx ready
    for (int k2 = 0; k2 < 8; ++k2) {
      int n = grp + k2*16;
      int e0 = rowstart[n], e1 = rowstart[n+1];
      float acc = 0.f;
      for (int e = e0; e < e1; ++e) {
        int pk = eidx[e];
        acc += hl[(pk >> 8)*36 + d] * rl[(pk & 255)*32 + d];
      }
      scratch[grp][d] = acc;
      float invd = 1.f / (float)((e1 - e0) > 0 ? (e1 - e0) : 1);
      float sa = 0.f, sh = 0.f;
      #pragma unroll
      for (int dd = 0; dd < 32; ++dd) {
        sa += scratch[grp][dd]*wm[dd];
        sh += hl[n*36 + dd]*ws[dd];
      }
      hnew[n*33 + d] = fmaxf(bj + invd*sa + sh, 0.f);
    }
    __syncthreads();
    for (int i = tid; i < NT*32; i += 512) {
      int row = i >> 5, col = i & 31;
      hl[row*36 + col] = hnew[row*33 + col];
    }
    #pragma unroll
    for (int pass = 0; pass < 8; ++pass) {
      int col = (pass << 2) + (tid >> 7);
      int row = tid & 127;
      AT[(size_t)(l*32 + col)*NNODE + g*NT + row] = hnew[row*33 + col];
    }
    {
      float m = -1e30f;
      #pragma unroll
      for (int k2 = 0; k2 < 8; ++k2) m = fmaxf(m, hnew[(grp + k2*16)*33 + d]);
      scratch[grp][d] = m;
    }
    __syncthreads();
    if (tid < 32) {
      float m = -1e30f;
      #pragma unroll
      for (int p2 = 0; p2 < 16; ++p2) m = fmaxf(m, scratch[p2][tid]);
      ghid0[g*96 + l*32 + tid] = m;
    }
    __syncthreads();
  }
}

// ---------------------------------------------------------------- k_gemm1m : MFMA bf16, GI f32 [node][576]
__global__ __launch_bounds__(256) void k_gemm1m(
    const float* __restrict__ AT, const float* __restrict__ gbias,
    const unsigned short* __restrict__ WT1bt, const float* __restrict__ bcat,
    float* __restrict__ GI) {
  __shared__ unsigned short As[128*104];
  int m0 = blockIdx.x * 128;
  int tid = threadIdx.x;
  for (int i = tid; i < 96*32; i += 256) {
    int r = i >> 5, c4 = i & 31;
    float4 v = *(const float4*)&AT[(size_t)r*NNODE + m0 + c4*4];
    float b = gbias[r];
    As[(c4*4+0)*104 + r] = f2bf(fmaxf(v.x+b,0.f));
    As[(c4*4+1)*104 + r] = f2bf(fmaxf(v.y+b,0.f));
    As[(c4*4+2)*104 + r] = f2bf(fmaxf(v.z+b,0.f));
    As[(c4*4+3)*104 + r] = f2bf(fmaxf(v.w+b,0.f));
  }
  __syncthreads();
  int w = tid >> 6, l = tid & 63;
  int lr = l & 15, lh = l >> 4;
  bf16x8 afr[2][3];
  #pragma unroll
  for (int tm = 0; tm < 2; ++tm)
    #pragma unroll
    for (int kc = 0; kc < 3; ++kc)
      afr[tm][kc] = *(const bf16x8*)&As[((w*2+tm)*16 + lr)*104 + kc*32 + lh*8];
  for (int nb = 0; nb < 9; ++nb) {
    int n0 = nb*64;
    #pragma unroll
    for (int tn = 0; tn < 4; ++tn) {
      int col = n0 + tn*16 + lr;
      const unsigned short* bp = WT1bt + (size_t)col*96 + lh*8;
      bf16x8 b0 = *(const bf16x8*)(bp);
      bf16x8 b1 = *(const bf16x8*)(bp + 32);
      bf16x8 b2 = *(const bf16x8*)(bp + 64);
      float bb = bcat[col];
      #pragma unroll
      for (int tm = 0; tm < 2; ++tm) {
        f32x4 acc = {bb, bb, bb, bb};
        acc = __builtin_amdgcn_mfma_f32_16x16x32_bf16(afr[tm][0], b0, acc, 0, 0, 0);
        acc = __builtin_amdgcn_mfma_f32_16x16x32_bf16(afr[tm][1], b1, acc, 0, 0, 0);
        acc = __builtin_amdgcn_mfma_f32_16x16x32_bf16(afr[tm][2], b2, acc, 0, 0, 0);
        int rbase = m0 + (w*2+tm)*16 + lh*4;
        #pragma unroll
        for (int r = 0; r < 4; ++r)
          __builtin_nontemporal_store(acc[r], &GI[(size_t)(rbase + r)*576 + col]);
      }
    }
  }
}

// ---------------------------------------------------------------- k_grup : gru blocks (0..255) + path blocks (256..511)
#define PIN4(v) asm volatile("" : "+v"(v.x), "+v"(v.y), "+v"(v.z), "+v"(v.w))
#define DOT16(acc, W0,W1,W2,W3, X0,X1,X2,X3) \
  acc += W0.x*X0.x + W0.y*X0.y + W0.z*X0.z + W0.w*X0.w \
       + W1.x*X1.x + W1.y*X1.y + W1.z*X1.z + W1.w*X1.w \
       + W2.x*X2.x + W2.y*X2.y + W2.z*X2.z + W2.w*X2.w \
       + W3.x*X3.x + W3.y*X3.y + W3.z*X3.z + W3.w*X3.w

union GPShared {
  struct { float h_lds[4][96]; float part[4][288][9]; } g;
  struct { float wsh[96*32]; float bsh[96]; float hbuf[128*33]; } p;
};

__global__ __launch_bounds__(576, 2) void k_grup(
    const float* __restrict__ Whh_f, const float* __restrict__ bhh_f,
    const float* __restrict__ Whh_b, const float* __restrict__ bhh_b,
    const float* __restrict__ GI, const float* __restrict__ ghid0,
    float* __restrict__ AT2,
    const float* __restrict__ XI, const int* __restrict__ in_rels,
    const int* __restrict__ labels, const float* __restrict__ pWhh,
    const float* __restrict__ pbhh, float* __restrict__ last) {
  __shared__ GPShared sm;
  int bx = blockIdx.x;
  int tid = threadIdx.x;
  if (bx < 256) {
    // ------------------------- GRU (R9 structure, proven 219us)
    float (*h_lds)[96] = sm.g.h_lds;
    float (*part)[288][9] = sm.g.part;
    int dir = bx >> 7;
    int gbase = (bx & 127) * 4;
    int c = tid % 96;
    int p = tid / 96;
    bool fin = (tid < 384);
    int s = p;
    const float* Whh = dir ? Whh_b : Whh_f;
    const float4* wr0 = (const float4*)(Whh + (size_t)c*96 + p*16);
    const float4* wr1 = (const float4*)(Whh + (size_t)(96+c)*96 + p*16);
    const float4* wr2 = (const float4*)(Whh + (size_t)(192+c)*96 + p*16);
    float4 wa0=wr0[0], wa1=wr0[1], wa2=wr0[2], wa3=wr0[3];
    float4 wb0=wr1[0], wb1=wr1[1], wb2=wr1[2], wb3=wr1[3];
    float4 wc0=wr2[0], wc1=wr2[1], wc2=wr2[2], wc3=wr2[3];
    float bh0=0.f, bh1=0.f, bh2=0.f;
    float gi0=0.f, gi1=0.f, gi2=0.f;
    if (fin) {
      const float* bhh = dir ? bhh_b : bhh_f;
      bh0 = bhh[c]; bh1 = bhh[96+c]; bh2 = bhh[192+c];
      h_lds[s][c] = ghid0[(gbase+s)*96 + c];
      int pos0 = dir ? 127 : 0;
      const float* gg = GI + (size_t)((gbase+s)*128 + pos0)*576 + dir*288;
      gi0 = gg[c]; gi1 = gg[96+c]; gi2 = gg[192+c];
    }
    __syncthreads();
    for (int t = 0; t < 128; ++t) {
      PIN4(wa0); PIN4(wa1); PIN4(wa2); PIN4(wa3);
      PIN4(wb0); PIN4(wb1); PIN4(wb2); PIN4(wb3);
      PIN4(wc0); PIN4(wc1); PIN4(wc2); PIN4(wc3);
      int pos = dir ? (127-t) : t;
      float gn0=0.f, gn1=0.f, gn2=0.f;
      if (fin && t < 127) {
        int posn = dir ? (126-t) : (t+1);
        const float* gg = GI + (size_t)((gbase+s)*128 + posn)*576 + dir*288;
        gn0 = gg[c]; gn1 = gg[96+c]; gn2 = gg[192+c];
      }
      #pragma unroll
      for (int s4 = 0; s4 < 4; ++s4) {
        const float4* hh = (const float4*)&h_lds[s4][p*16];
        float4 x0=hh[0], x1=hh[1], x2=hh[2], x3=hh[3];
        float q0=0.f, q1=0.f, q2=0.f;
        DOT16(q0, wa0,wa1,wa2,wa3, x0,x1,x2,x3);
        DOT16(q1, wb0,wb1,wb2,wb3, x0,x1,x2,x3);
        DOT16(q2, wc0,wc1,wc2,wc3, x0,x1,x2,x3);
        part[s4][c][p]     = q0;
        part[s4][96+c][p]  = q1;
        part[s4][192+c][p] = q2;
      }
      __syncthreads();
      if (fin) {
        const float* pr = part[s][c];
        const float* pz = part[s][96+c];
        const float* pn = part[s][192+c];
        float ghr = pr[0]+pr[1]+pr[2]+pr[3]+pr[4]+pr[5] + bh0;
        float ghz = pz[0]+pz[1]+pz[2]+pz[3]+pz[4]+pz[5] + bh1;
        float ghn = pn[0]+pn[1]+pn[2]+pn[3]+pn[4]+pn[5] + bh2;
        float r  = sigm(gi0 + ghr);
        float z  = sigm(gi1 + ghz);
        float nn = tanhf(gi2 + r*ghn);
        float hv = (1.f - z)*nn + z*h_lds[s][c];
        h_lds[s][c] = hv;
        AT2[(size_t)(dir*96 + c)*NNODE + (gbase+s)*128 + pos] = fmaxf(hv, 0.f);
        gi0 = gn0; gi1 = gn1; gi2 = gn2;
      }
      __syncthreads();
    }
  } else {
    // ------------------------- PATH (3-step GRU over XI)
    float* wsh = sm.p.wsh;
    float* bsh = sm.p.bsh;
    float* hbuf = sm.p.hbuf;
    for (int i = tid; i < 96*32; i += 576) wsh[i] = pWhh[i];
    if (tid < 96) bsh[tid] = pbhh[tid];
    __syncthreads();
    if (tid < 128) {
      int pth = (bx - 256)*128 + tid;
      int b = pth >> 6, pp = pth & 63;
      int rid0 = in_rels[b*1024 + (pp >> 3)];
      int rid1 = labels[b];
      int rid2 = in_rels[b*1024 + 8 + (pp & 7)];
      float* hs = &hbuf[tid*33];
      {
        const float* xi = XI + rid0*96;
        #pragma unroll
        for (int gg = 0; gg < 32; ++gg) {
          float r = sigm(xi[gg] + bsh[gg]);
          float z = sigm(xi[32+gg] + bsh[32+gg]);
          float nn = tanhf(xi[64+gg] + r*bsh[64+gg]);
          hs[gg] = (1.f - z)*nn;
        }
      }
      float4 h4[8];
      #pragma unroll
      for (int q = 0; q < 8; ++q) h4[q] = make_float4(hs[4*q], hs[4*q+1], hs[4*q+2], hs[4*q+3]);
      for (int s = 0; s < 2; ++s) {
        const float* xi = XI + (s == 0 ? rid1 : rid2)*96;
        for (int gg = 0; gg < 32; ++gg) {
          float ar = bsh[gg], az = bsh[32+gg], an = bsh[64+gg];
          const float4* wr = (const float4*)&wsh[gg*32];
          const float4* wz = (const float4*)&wsh[(32+gg)*32];
          const float4* wn = (const float4*)&wsh[(64+gg)*32];
          #pragma unroll
          for (int q = 0; q < 8; ++q) {
            float4 hv = h4[q]; float4 w;
            w = wr[q]; ar += hv.x*w.x + hv.y*w.y + hv.z*w.z + hv.w*w.w;
            w = wz[q]; az += hv.x*w.x + hv.y*w.y + hv.z*w.z + hv.w*w.w;
            w = wn[q]; an += hv.x*w.x + hv.y*w.y + hv.z*w.z + hv.w*w.w;
          }
          float r = sigm(xi[gg] + ar);
          float z = sigm(xi[32+gg] + az);
          float nn = tanhf(xi[64+gg] + r*an);
          hs[gg] = (1.f - z)*nn + z*hs[gg];
        }
        #pragma unroll
        for (int q = 0; q < 8; ++q) h4[q] = make_float4(hs[4*q], hs[4*q+1], hs[4*q+2], hs[4*q+3]);
      }
      float* lp = last + (size_t)pth*32;
      #pragma unroll
      for (int dd = 0; dd < 32; ++dd) lp[dd] = hs[dd];
    }
  }
}

// ---------------------------------------------------------------- k_gemm2m : MFMA bf16 Wo-GEMM + fused pooling
__global__ __launch_bounds__(384) void k_gemm2m(
    const float* __restrict__ AT2, const unsigned short* __restrict__ WoBt,
    const float* __restrict__ Wob, float* __restrict__ goutb,
    float* __restrict__ headb, float* __restrict__ tailb) {
  __shared__ unsigned short As[64*104];
  int m0 = blockIdx.x * 64;
  int g = m0 >> 7;
  int tid = threadIdx.x;
  int w = tid / 64, l = tid & 63;
  int lr = l & 15, lh = l >> 4;
  int col = w*16 + lr;
  float bb = Wob[col];
  f32x4 acc[4];
  #pragma unroll
  for (int mt = 0; mt < 4; ++mt) acc[mt] = (f32x4){bb, bb, bb, bb};
  for (int kc = 0; kc < 2; ++kc) {
    if (kc) __syncthreads();
    for (int i = tid; i < 1536; i += 384) {
      int r = i >> 4, c4 = i & 15;
      float4 v = *(const float4*)&AT2[(size_t)(kc*96 + r)*NNODE + m0 + c4*4];
      As[(c4*4+0)*104 + r] = f2bf(v.x);
      As[(c4*4+1)*104 + r] = f2bf(v.y);
      As[(c4*4+2)*104 + r] = f2bf(v.z);
      As[(c4*4+3)*104 + r] = f2bf(v.w);
    }
    __syncthreads();
    const unsigned short* bp = WoBt + (size_t)col*192 + kc*96 + lh*8;
    bf16x8 b0 = *(const bf16x8*)(bp);
    bf16x8 b1 = *(const bf16x8*)(bp + 32);
    bf16x8 b2 = *(const bf16x8*)(bp + 64);
    #pragma unroll
    for (int mt = 0; mt < 4; ++mt) {
      const unsigned short* ap = &As[(mt*16 + lr)*104 + lh*8];
      bf16x8 a0 = *(const bf16x8*)(ap);
      bf16x8 a1 = *(const bf16x8*)(ap + 32);
      bf16x8 a2 = *(const bf16x8*)(ap + 64);
      acc[mt] = __builtin_amdgcn_mfma_f32_16x16x32_bf16(a0, b0, acc[mt], 0, 0, 0);
      acc[mt] = __builtin_amdgcn_mfma_f32_16x16x32_bf16(a1, b1, acc[mt], 0, 0, 0);
      acc[mt] = __builtin_amdgcn_mfma_f32_16x16x32_bf16(a2, b2, acc[mt], 0, 0, 0);
    }
  }
  float colsum = 0.f;
  bool hb = ((m0 & 127) == 0) && (lh == 0);
  #pragma unroll
  for (int mt = 0; mt < 4; ++mt) {
    #pragma unroll
    for (int r = 0; r < 4; ++r) {
      float v = fmaxf(acc[mt][r], 0.f);
      colsum += v;
      if (hb && mt == 0) {
        if (r == 0) headb[g*96 + col] = v;
        if (r == 1) tailb[g*96 + col] = v;
      }
    }
  }
  colsum += __shfl_xor(colsum, 16);
  colsum += __shfl_xor(colsum, 32);
  if (lh == 0) atomicAdd(&goutb[g*96 + col], colsum);
}

// ---------------------------------------------------------------- k_final
__global__ __launch_bounds__(64) void k_final(
    const float* __restrict__ last, const float* __restrict__ r3,
    const int* __restrict__ labels, const float* __restrict__ goutb,
    const float* __restrict__ headb, const float* __restrict__ tailb,
    const float* __restrict__ fcW, const float* __restrict__ fcb,
    float* __restrict__ out) {
  __shared__ float red[64*33];
  __shared__ float gpl[32];
  int b = blockIdx.x, lane = threadIdx.x;
  const float* rl = r3 + labels[b]*32;
  float l32[32];
  {
    const float4* lr = (const float4*)(last + (size_t)(b*64 + lane)*32);
    #pragma unroll
    for (int q = 0; q < 8; ++q) {
      float4 v = lr[q];
      l32[4*q+0]=v.x; l32[4*q+1]=v.y; l32[4*q+2]=v.z; l32[4*q+3]=v.w;
    }
  }
  float s = 0.f;
  #pragma unroll
  for (int d = 0; d < 32; ++d) s += l32[d]*rl[d];
  float mx = s;
  #pragma unroll
  for (int off = 32; off > 0; off >>= 1) mx = fmaxf(mx, __shfl_xor(mx, off));
  float e = __expf(s - mx);
  float den = e;
  #pragma unroll
  for (int off = 32; off > 0; off >>= 1) den += __shfl_xor(den, off);
  float att = e / den;
  #pragma unroll
  for (int d = 0; d < 32; ++d) red[lane*33 + d] = att*l32[d];
  __syncthreads();
  if (lane < 32) {
    float gp = 0.f;
    for (int p2 = 0; p2 < 64; ++p2) gp += red[p2*33 + lane];
    gpl[lane] = gp;
  }
  __syncthreads();
  float acc = 0.f;
  for (int i = lane; i < 352; i += 64) {
    float v;
    if (i < 96)       v = goutb[b*96 + i] * 0.0078125f;
    else if (i < 192) v = headb[b*96 + (i-96)];
    else if (i < 288) v = tailb[b*96 + (i-192)];
    else if (i < 320) v = rl[i-288];
    else              v = gpl[i-320];
    acc += v*fcW[i];
  }
  #pragma unroll
  for (int off = 32; off > 0; off >>= 1) acc += __shfl_xor(acc, off);
  if (lane == 0) out[b] = acc + fcb[0];
}

// ---------------------------------------------------------------- launch
extern "C" void kernel_launch(void* const* d_in, const int* in_sizes, int n_in,
                              void* d_out, int out_size, void* d_ws, size_t ws_size,
                              hipStream_t stream) {
  const float* feat       = (const float*)d_in[0];
  const int*   out_rels   = (const int*)d_in[1];
  const int*   in_rels    = (const int*)d_in[2];
  const int*   r_label_nd = (const int*)d_in[3];
  const int*   src        = (const int*)d_in[4];
  const int*   dst        = (const int*)d_in[5];
  const int*   etype      = (const int*)d_in[6];
  const int*   rel_labels = (const int*)d_in[7];
  const float* rel_emb    = (const float*)d_in[8];
  const float* w2e_W      = (const float*)d_in[9];
  const float* w2e_b      = (const float*)d_in[10];
  const float* W_msg      = (const float*)d_in[11];
  const float* W_self     = (const float*)d_in[12];
  const float* b_gnn      = (const float*)d_in[13];
  const float* W_rel      = (const float*)d_in[14];
  const float* gru_bias   = (const float*)d_in[15];
  const float* Wih_f      = (const float*)d_in[16];
  const float* Whh_f      = (const float*)d_in[17];
  const float* bih_f      = (const float*)d_in[18];
  const float* bhh_f      = (const float*)d_in[19];
  const float* Wih_b      = (const float*)d_in[20];
  const float* Whh_b      = (const float*)d_in[21];
  const float* bih_b      = (const float*)d_in[22];
  const float* bhh_b      = (const float*)d_in[23];
  const float* Wo_W       = (const float*)d_in[24];
  const float* Wo_b       = (const float*)d_in[25];
  const float* pWih       = (const float*)d_in[26];
  const float* pWhh       = (const float*)d_in[27];
  const float* pbih       = (const float*)d_in[28];
  const float* pbhh       = (const float*)d_in[29];
  const float* fcW        = (const float*)d_in[30];
  const float* fcb        = (const float*)d_in[31];
  float* out = (float*)d_out;

  float* p = (float*)d_ws;
  float* R1    = p; p += (size_t)NNODE*192;   // AT (96xN) then AT2 (192xN)
  float* AT    = R1;
  float* AT2   = R1;
  float* GI    = p; p += (size_t)NNODE*576 + 16;
  float* r123  = p; p += 3*NREL*32;
  unsigned short* WT1bt = (unsigned short*)p; p += (576*96)/2;
  unsigned short* WoBt  = (unsigned short*)p; p += (96*192)/2;
  float* bcat  = p; p += 576;
  float* XI    = p; p += NREL*96;
  float* ghid0 = p; p += BB*96;
  float* goutb = p; p += BB*96;
  float* headb = p; p += BB*96;
  float* tailb = p; p += BB*96;
  float* lastb = p; p += (size_t)BB*64*32;

  hipMemsetAsync(goutb, 0, BB*96*sizeof(float), stream);
  k_rel2<<<NREL, 96, 0, stream>>>(rel_emb, W_rel, pWih, pbih, r123, XI);
  k_wt1<<<(576*96+255)/256, 256, 0, stream>>>(Wih_f, Wih_b, bih_f, bih_b, Wo_W,
                                              WT1bt, WoBt, bcat);
  k_gnn3<<<BB, 512, 0, stream>>>(feat, out_rels, in_rels, r_label_nd,
                                 w2e_W, w2e_b, rel_emb, r123, src, dst, etype,
                                 W_msg, W_self, b_gnn, AT, ghid0);
  k_gemm1m<<<512, 256, 0, stream>>>(AT, gru_bias, WT1bt, bcat, GI);
  k_grup<<<512, 576, 0, stream>>>(Whh_f, bhh_f, Whh_b, bhh_b, GI, ghid0, AT2,
                                  XI, in_rels, rel_labels, pWhh, pbhh, lastb);
  k_gemm2m<<<1024, 384, 0, stream>>>(AT2, WoBt, Wo_b, goutb, headb, tailb);
  k_final<<<BB, 64, 0, stream>>>(lastb, r123 + 2*NREL*32, rel_labels,
                                 goutb, headb, tailb, fcW, fcb, out);
}

// Round 16
// 530.689 us; speedup vs baseline: 1.0138x; 1.0138x over previous
//
#include <hip/hip_runtime.h>
#include <math.h>

#define BB 512
#define NT 128
#define NREL 201
#define NNODE (BB*NT)
#define NEDGE (NNODE*16)

typedef float f32x4 __attribute__((ext_vector_type(4)));
typedef __attribute__((ext_vector_type(8))) short bf16x8;

__device__ __forceinline__ float sigm(float x) { return 1.f/(1.f + __expf(-x)); }

__device__ __forceinline__ unsigned short f2bf(float f) {
  unsigned u; __builtin_memcpy(&u, &f, 4);
  unsigned r = u + 0x7fffu + ((u >> 16) & 1u);   // RNE
  return (unsigned short)(r >> 16);
}

// ---------------------------------------------------------------- k_rel2 : per-row rel chain + XI (201 blocks x 96)
__global__ __launch_bounds__(96) void k_rel2(const float* __restrict__ rel_emb,
                                             const float* __restrict__ W_rel,
                                             const float* __restrict__ pWih,
                                             const float* __restrict__ pbih,
                                             float* __restrict__ r123,
                                             float* __restrict__ XI) {
  __shared__ float ra[32], rb[32];
  int r = blockIdx.x, tid = threadIdx.x;
  if (tid < 32) ra[tid] = rel_emb[r*32 + tid];
  __syncthreads();
  if (tid < 32) {
    float s = 0.f;
    #pragma unroll
    for (int d = 0; d < 32; ++d) s += ra[d]*W_rel[d*32 + tid];
    rb[tid] = s; r123[0*NREL*32 + r*32 + tid] = s;
  }
  __syncthreads();
  if (tid < 32) {
    float s = 0.f;
    #pragma unroll
    for (int d = 0; d < 32; ++d) s += rb[d]*W_rel[1024 + d*32 + tid];
    ra[tid] = s; r123[1*NREL*32 + r*32 + tid] = s;
  }
  __syncthreads();
  if (tid < 32) {
    float s = 0.f;
    #pragma unroll
    for (int d = 0; d < 32; ++d) s += ra[d]*W_rel[2048 + d*32 + tid];
    rb[tid] = s; r123[2*NREL*32 + r*32 + tid] = s;
  }
  __syncthreads();
  float s = pbih[tid];
  #pragma unroll
  for (int d = 0; d < 32; ++d) s += rb[d]*pWih[tid*32 + d];
  XI[r*96 + tid] = s;
}

// ---------------------------------------------------------------- k_wt1 : WT1bt[576][96] bf16 ; WoBt[96][192] bf16 ; bcat f32
__global__ __launch_bounds__(256) void k_wt1(const float* __restrict__ Wih_f,
                                             const float* __restrict__ Wih_b,
                                             const float* __restrict__ bih_f,
                                             const float* __restrict__ bih_b,
                                             const float* __restrict__ Wo_W,
                                             unsigned short* __restrict__ WT1bt,
                                             unsigned short* __restrict__ WoBt,
                                             float* __restrict__ bcat) {
  int i = blockIdx.x*256 + threadIdx.x;
  if (i < 576*96) {
    int j = i / 96;
    float v = (j < 288) ? Wih_f[i] : Wih_b[i - 288*96];
    WT1bt[i] = f2bf(v);
  }
  if (i < 96*192) {
    int j = i / 192, k = i - j*192;
    WoBt[i] = f2bf(Wo_W[k*96 + j]);
  }
  if (i < 576) bcat[i] = (i < 288) ? bih_f[i] : bih_b[i-288];
}

// ---------------------------------------------------------------- sem attention reading LDS rel table
__device__ __forceinline__ void sem_att_l(const float* __restrict__ rl,
                                          const int rels[8], const float tgt[32],
                                          float out[32]) {
  float dots[8]; float mx = -1e30f;
  #pragma unroll
  for (int k = 0; k < 8; ++k) {
    const float4* er = (const float4*)&rl[rels[k]*32];
    float s = 0.f;
    #pragma unroll
    for (int q = 0; q < 8; ++q) {
      float4 v = er[q];
      s += v.x*tgt[4*q+0] + v.y*tgt[4*q+1] + v.z*tgt[4*q+2] + v.w*tgt[4*q+3];
    }
    dots[k] = s; mx = fmaxf(mx, s);
  }
  float den = 0.f;
  #pragma unroll
  for (int k = 0; k < 8; ++k) { float e = __expf(dots[k]-mx); dots[k] = e; den += e; }
  float inv = 1.f/den;
  #pragma unroll
  for (int d = 0; d < 32; ++d) out[d] = 0.f;
  #pragma unroll
  for (int k = 0; k < 8; ++k) {
    const float4* er = (const float4*)&rl[rels[k]*32];
    float a = dots[k]*inv;
    #pragma unroll
    for (int q = 0; q < 8; ++q) {
      float4 v = er[q];
      out[4*q+0] += a*v.x; out[4*q+1] += a*v.y; out[4*q+2] += a*v.z; out[4*q+3] += a*v.w;
    }
  }
}

// ---------------------------------------------------------------- k_gnn3 : sem + 3 GNN layers fused, CSR gather
__global__ __launch_bounds__(512) void k_gnn3(
    const float* __restrict__ feat, const int* __restrict__ out_rels,
    const int* __restrict__ in_rels, const int* __restrict__ r_label_node,
    const float* __restrict__ w2e_W, const float* __restrict__ w2e_b,
    const float* __restrict__ rel_emb, const float* __restrict__ r123,
    const int* __restrict__ src, const int* __restrict__ dst, const int* __restrict__ etype,
    const float* __restrict__ W_msg, const float* __restrict__ W_self,
    const float* __restrict__ b_gnn,
    float* __restrict__ AT, float* __restrict__ ghid0) {
  __shared__ __align__(16) float hl[NT*36];
  __shared__ __align__(16) float hnew[NT*33];
  __shared__ __align__(16) float rl[NREL*32];
  __shared__ unsigned short eidx[2048];
  __shared__ float scratch[16][32];
  __shared__ int cnt[128], fill[128], scanv[128], rowstart[129];
  int g = blockIdx.x;
  int tid = threadIdx.x;
  int d = tid & 31, grp = tid >> 5;

  for (int i = tid; i < NREL*32; i += 512) rl[i] = rel_emb[i];
  if (tid < 128) { cnt[tid] = 0; fill[tid] = 0; }
  __syncthreads();
  for (int i = tid; i < 2048; i += 512)
    atomicAdd(&cnt[dst[g*2048 + i] - g*NT], 1);
  __syncthreads();
  if (tid < 128) scanv[tid] = cnt[tid];
  __syncthreads();
  #pragma unroll
  for (int off = 1; off < 128; off <<= 1) {
    int v = 0;
    if (tid < 128 && tid >= off) v = scanv[tid - off];
    __syncthreads();
    if (tid < 128) scanv[tid] += v;
    __syncthreads();
  }
  if (tid < 128) { rowstart[tid+1] = scanv[tid]; if (tid == 0) rowstart[0] = 0; }
  __syncthreads();
  for (int i = tid; i < 2048; i += 512) {
    int e = g*2048 + i;
    int dl = dst[e] - g*NT;
    int slot = rowstart[dl] + atomicAdd(&fill[dl], 1);
    eidx[slot] = (unsigned short)(((src[e] - g*NT) << 8) | etype[e]);
  }
  // sem: threads 0..127 compute their node's h0 into hl (reads rl from LDS)
  if (tid < 128) {
    int n = g*NT + tid;
    float tgt[32];
    {
      const float4* tr = (const float4*)&rl[r_label_node[n]*32];
      #pragma unroll
      for (int q = 0; q < 8; ++q) {
        float4 v = tr[q];
        tgt[4*q+0]=v.x; tgt[4*q+1]=v.y; tgt[4*q+2]=v.z; tgt[4*q+3]=v.w;
      }
    }
    int ro[8], ri[8];
    #pragma unroll
    for (int k = 0; k < 8; ++k) { ro[k] = out_rels[n*8+k]; ri[k] = in_rels[n*8+k]; }
    float osem[32], isem[32];
    sem_att_l(rl, ro, tgt, osem);
    sem_att_l(rl, ri, tgt, isem);
    const float4* fr = (const float4*)(feat + (size_t)n*16);
    #pragma unroll
    for (int q = 0; q < 4; ++q) {
      float4 v = fr[q];
      hl[tid*36 + 4*q+0] = v.x; hl[tid*36 + 4*q+1] = v.y;
      hl[tid*36 + 4*q+2] = v.z; hl[tid*36 + 4*q+3] = v.w;
    }
    #pragma unroll
    for (int j = 0; j < 16; ++j) {
      float s = w2e_b[j];
      #pragma unroll
      for (int dd = 0; dd < 32; ++dd) s += osem[dd]*w2e_W[dd*16+j] + isem[dd]*w2e_W[(32+dd)*16+j];
      hl[tid*36 + 16 + j] = sigm(s);
    }
  }

  for (int l = 0; l < 3; ++l) {
    if (l > 0) {
      const float* rsrc = r123 + (size_t)(l-1)*NREL*32;
      for (int i = tid; i < NREL*32; i += 512) rl[i] = rsrc[i];
    }
    float wm[32], ws[32];
    #pragma unroll
    for (int dd = 0; dd < 32; ++dd) {
      wm[dd] = W_msg[l*1024 + dd*32 + d];
      ws[dd] = W_self[l*1024 + dd*32 + d];
    }
    float bj = b_gnn[l*32 + d];
    __syncthreads();                       // rl + hl + eidx ready
    for (int k2 = 0; k2 < 8; ++k2) {
      int n = grp + k2*16;
      int e0 = rowstart[n], e1 = rowstart[n+1];
      float acc = 0.f;
      for (int e = e0; e < e1; ++e) {
        int pk = eidx[e];
        acc += hl[(pk >> 8)*36 + d] * rl[(pk & 255)*32 + d];
      }
      scratch[grp][d] = acc;
      float invd = 1.f / (float)((e1 - e0) > 0 ? (e1 - e0) : 1);
      float sa = 0.f, sh = 0.f;
      #pragma unroll
      for (int dd = 0; dd < 32; ++dd) {
        sa += scratch[grp][dd]*wm[dd];
        sh += hl[n*36 + dd]*ws[dd];
      }
      hnew[n*33 + d] = fmaxf(bj + invd*sa + sh, 0.f);
    }
    __syncthreads();
    for (int i = tid; i < NT*32; i += 512) {
      int row = i >> 5, col = i & 31;
      hl[row*36 + col] = hnew[row*33 + col];
    }
    #pragma unroll
    for (int pass = 0; pass < 8; ++pass) {
      int col = (pass << 2) + (tid >> 7);
      int row = tid & 127;
      AT[(size_t)(l*32 + col)*NNODE + g*NT + row] = hnew[row*33 + col];
    }
    {
      float m = -1e30f;
      #pragma unroll
      for (int k2 = 0; k2 < 8; ++k2) m = fmaxf(m, hnew[(grp + k2*16)*33 + d]);
      scratch[grp][d] = m;
    }
    __syncthreads();
    if (tid < 32) {
      float m = -1e30f;
      #pragma unroll
      for (int p2 = 0; p2 < 16; ++p2) m = fmaxf(m, scratch[p2][tid]);
      ghid0[g*96 + l*32 + tid] = m;
    }
    __syncthreads();
  }
}

// ---------------------------------------------------------------- k_gemm1m : MFMA bf16, GI f32 [node][576]
__global__ __launch_bounds__(256) void k_gemm1m(
    const float* __restrict__ AT, const float* __restrict__ gbias,
    const unsigned short* __restrict__ WT1bt, const float* __restrict__ bcat,
    float* __restrict__ GI) {
  __shared__ unsigned short As[128*104];
  int m0 = blockIdx.x * 128;
  int tid = threadIdx.x;
  for (int i = tid; i < 96*32; i += 256) {
    int r = i >> 5, c4 = i & 31;
    float4 v = *(const float4*)&AT[(size_t)r*NNODE + m0 + c4*4];
    float b = gbias[r];
    As[(c4*4+0)*104 + r] = f2bf(fmaxf(v.x+b,0.f));
    As[(c4*4+1)*104 + r] = f2bf(fmaxf(v.y+b,0.f));
    As[(c4*4+2)*104 + r] = f2bf(fmaxf(v.z+b,0.f));
    As[(c4*4+3)*104 + r] = f2bf(fmaxf(v.w+b,0.f));
  }
  __syncthreads();
  int w = tid >> 6, l = tid & 63;
  int lr = l & 15, lh = l >> 4;
  bf16x8 afr[2][3];
  #pragma unroll
  for (int tm = 0; tm < 2; ++tm)
    #pragma unroll
    for (int kc = 0; kc < 3; ++kc)
      afr[tm][kc] = *(const bf16x8*)&As[((w*2+tm)*16 + lr)*104 + kc*32 + lh*8];
  for (int nb = 0; nb < 9; ++nb) {
    int n0 = nb*64;
    #pragma unroll
    for (int tn = 0; tn < 4; ++tn) {
      int col = n0 + tn*16 + lr;
      const unsigned short* bp = WT1bt + (size_t)col*96 + lh*8;
      bf16x8 b0 = *(const bf16x8*)(bp);
      bf16x8 b1 = *(const bf16x8*)(bp + 32);
      bf16x8 b2 = *(const bf16x8*)(bp + 64);
      float bb = bcat[col];
      #pragma unroll
      for (int tm = 0; tm < 2; ++tm) {
        f32x4 acc = {bb, bb, bb, bb};
        acc = __builtin_amdgcn_mfma_f32_16x16x32_bf16(afr[tm][0], b0, acc, 0, 0, 0);
        acc = __builtin_amdgcn_mfma_f32_16x16x32_bf16(afr[tm][1], b1, acc, 0, 0, 0);
        acc = __builtin_amdgcn_mfma_f32_16x16x32_bf16(afr[tm][2], b2, acc, 0, 0, 0);
        int rbase = m0 + (w*2+tm)*16 + lh*4;
        #pragma unroll
        for (int r = 0; r < 4; ++r)
          __builtin_nontemporal_store(acc[r], &GI[(size_t)(rbase + r)*576 + col]);
      }
    }
  }
}

// ---------------------------------------------------------------- k_gru : S=4, 576 thr, part[] reduce (R9 proven, 219us)
#define PIN4(v) asm volatile("" : "+v"(v.x), "+v"(v.y), "+v"(v.z), "+v"(v.w))
#define DOT16(acc, W0,W1,W2,W3, X0,X1,X2,X3) \
  acc += W0.x*X0.x + W0.y*X0.y + W0.z*X0.z + W0.w*X0.w \
       + W1.x*X1.x + W1.y*X1.y + W1.z*X1.z + W1.w*X1.w \
       + W2.x*X2.x + W2.y*X2.y + W2.z*X2.z + W2.w*X2.w \
       + W3.x*X3.x + W3.y*X3.y + W3.z*X3.z + W3.w*X3.w

__global__ __launch_bounds__(576, 1) void k_gru(
    const float* __restrict__ Whh_f, const float* __restrict__ bhh_f,
    const float* __restrict__ Whh_b, const float* __restrict__ bhh_b,
    const float* __restrict__ GI, const float* __restrict__ ghid0,
    float* __restrict__ AT2) {
  __shared__ __align__(16) float h_lds[4][96];
  __shared__ float part[4][288][9];
  int bx = blockIdx.x;                  // 256 blocks = 1/CU
  int dir = bx >> 7;
  int gbase = (bx & 127) * 4;
  int tid = threadIdx.x;
  int c = tid % 96;
  int p = tid / 96;
  bool fin = (tid < 384);
  int s = p;

  const float* Whh = dir ? Whh_b : Whh_f;
  const float4* wr0 = (const float4*)(Whh + (size_t)c*96 + p*16);
  const float4* wr1 = (const float4*)(Whh + (size_t)(96+c)*96 + p*16);
  const float4* wr2 = (const float4*)(Whh + (size_t)(192+c)*96 + p*16);
  float4 wa0=wr0[0], wa1=wr0[1], wa2=wr0[2], wa3=wr0[3];
  float4 wb0=wr1[0], wb1=wr1[1], wb2=wr1[2], wb3=wr1[3];
  float4 wc0=wr2[0], wc1=wr2[1], wc2=wr2[2], wc3=wr2[3];

  float bh0=0.f, bh1=0.f, bh2=0.f;
  float gi0=0.f, gi1=0.f, gi2=0.f;
  if (fin) {
    const float* bhh = dir ? bhh_b : bhh_f;
    bh0 = bhh[c]; bh1 = bhh[96+c]; bh2 = bhh[192+c];
    h_lds[s][c] = ghid0[(gbase+s)*96 + c];
    int pos0 = dir ? 127 : 0;
    const float* g = GI + (size_t)((gbase+s)*128 + pos0)*576 + dir*288;
    gi0 = g[c]; gi1 = g[96+c]; gi2 = g[192+c];
  }
  __syncthreads();
  for (int t = 0; t < 128; ++t) {
    PIN4(wa0); PIN4(wa1); PIN4(wa2); PIN4(wa3);
    PIN4(wb0); PIN4(wb1); PIN4(wb2); PIN4(wb3);
    PIN4(wc0); PIN4(wc1); PIN4(wc2); PIN4(wc3);
    int pos = dir ? (127-t) : t;
    float gn0=0.f, gn1=0.f, gn2=0.f;
    if (fin && t < 127) {
      int posn = dir ? (126-t) : (t+1);
      const float* g = GI + (size_t)((gbase+s)*128 + posn)*576 + dir*288;
      gn0 = g[c]; gn1 = g[96+c]; gn2 = g[192+c];
    }
    #pragma unroll
    for (int s4 = 0; s4 < 4; ++s4) {
      const float4* hh = (const float4*)&h_lds[s4][p*16];
      float4 x0=hh[0], x1=hh[1], x2=hh[2], x3=hh[3];
      float q0=0.f, q1=0.f, q2=0.f;
      DOT16(q0, wa0,wa1,wa2,wa3, x0,x1,x2,x3);
      DOT16(q1, wb0,wb1,wb2,wb3, x0,x1,x2,x3);
      DOT16(q2, wc0,wc1,wc2,wc3, x0,x1,x2,x3);
      part[s4][c][p]     = q0;
      part[s4][96+c][p]  = q1;
      part[s4][192+c][p] = q2;
    }
    __syncthreads();
    if (fin) {
      const float* pr = part[s][c];
      const float* pz = part[s][96+c];
      const float* pn = part[s][192+c];
      float ghr = pr[0]+pr[1]+pr[2]+pr[3]+pr[4]+pr[5] + bh0;
      float ghz = pz[0]+pz[1]+pz[2]+pz[3]+pz[4]+pz[5] + bh1;
      float ghn = pn[0]+pn[1]+pn[2]+pn[3]+pn[4]+pn[5] + bh2;
      float r  = sigm(gi0 + ghr);
      float z  = sigm(gi1 + ghz);
      float nn = tanhf(gi2 + r*ghn);
      float hv = (1.f - z)*nn + z*h_lds[s][c];
      h_lds[s][c] = hv;
      AT2[(size_t)(dir*96 + c)*NNODE + (gbase+s)*128 + pos] = fmaxf(hv, 0.f);
      gi0 = gn0; gi1 = gn1; gi2 = gn2;
    }
    __syncthreads();
  }
}

// ---------------------------------------------------------------- k_gemm2m : MFMA bf16 Wo-GEMM + fused pooling
__global__ __launch_bounds__(384) void k_gemm2m(
    const float* __restrict__ AT2, const unsigned short* __restrict__ WoBt,
    const float* __restrict__ Wob, float* __restrict__ goutb,
    float* __restrict__ headb, float* __restrict__ tailb) {
  __shared__ unsigned short As[64*104];
  int m0 = blockIdx.x * 64;
  int g = m0 >> 7;
  int tid = threadIdx.x;
  int w = tid / 64, l = tid & 63;
  int lr = l & 15, lh = l >> 4;
  int col = w*16 + lr;
  float bb = Wob[col];
  f32x4 acc[4];
  #pragma unroll
  for (int mt = 0; mt < 4; ++mt) acc[mt] = (f32x4){bb, bb, bb, bb};
  for (int kc = 0; kc < 2; ++kc) {
    if (kc) __syncthreads();
    for (int i = tid; i < 1536; i += 384) {
      int r = i >> 4, c4 = i & 15;
      float4 v = *(const float4*)&AT2[(size_t)(kc*96 + r)*NNODE + m0 + c4*4];
      As[(c4*4+0)*104 + r] = f2bf(v.x);
      As[(c4*4+1)*104 + r] = f2bf(v.y);
      As[(c4*4+2)*104 + r] = f2bf(v.z);
      As[(c4*4+3)*104 + r] = f2bf(v.w);
    }
    __syncthreads();
    const unsigned short* bp = WoBt + (size_t)col*192 + kc*96 + lh*8;
    bf16x8 b0 = *(const bf16x8*)(bp);
    bf16x8 b1 = *(const bf16x8*)(bp + 32);
    bf16x8 b2 = *(const bf16x8*)(bp + 64);
    #pragma unroll
    for (int mt = 0; mt < 4; ++mt) {
      const unsigned short* ap = &As[(mt*16 + lr)*104 + lh*8];
      bf16x8 a0 = *(const bf16x8*)(ap);
      bf16x8 a1 = *(const bf16x8*)(ap + 32);
      bf16x8 a2 = *(const bf16x8*)(ap + 64);
      acc[mt] = __builtin_amdgcn_mfma_f32_16x16x32_bf16(a0, b0, acc[mt], 0, 0, 0);
      acc[mt] = __builtin_amdgcn_mfma_f32_16x16x32_bf16(a1, b1, acc[mt], 0, 0, 0);
      acc[mt] = __builtin_amdgcn_mfma_f32_16x16x32_bf16(a2, b2, acc[mt], 0, 0, 0);
    }
  }
  float colsum = 0.f;
  bool hb = ((m0 & 127) == 0) && (lh == 0);
  #pragma unroll
  for (int mt = 0; mt < 4; ++mt) {
    #pragma unroll
    for (int r = 0; r < 4; ++r) {
      float v = fmaxf(acc[mt][r], 0.f);
      colsum += v;
      if (hb && mt == 0) {
        if (r == 0) headb[g*96 + col] = v;
        if (r == 1) tailb[g*96 + col] = v;
      }
    }
  }
  colsum += __shfl_xor(colsum, 16);
  colsum += __shfl_xor(colsum, 32);
  if (lh == 0) atomicAdd(&goutb[g*96 + col], colsum);
}

// ---------------------------------------------------------------- k_path
__global__ __launch_bounds__(128) void k_path(
    const float* __restrict__ XI, const int* __restrict__ in_rels,
    const int* __restrict__ labels, const float* __restrict__ pWhh,
    const float* __restrict__ pbhh, float* __restrict__ last) {
  __shared__ __align__(16) float wsh[96*32];
  __shared__ float bsh[96];
  __shared__ float hbuf[128*33];
  int tid = threadIdx.x;
  for (int i = tid; i < 96*32; i += 128) wsh[i] = pWhh[i];
  if (tid < 96) bsh[tid] = pbhh[tid];
  int p = blockIdx.x*128 + tid;
  int b = p >> 6, pp = p & 63;
  int rid0 = in_rels[b*1024 + (pp >> 3)];
  int rid1 = labels[b];
  int rid2 = in_rels[b*1024 + 8 + (pp & 7)];
  __syncthreads();
  float* hs = &hbuf[tid*33];
  {
    const float* xi = XI + rid0*96;
    #pragma unroll
    for (int gg = 0; gg < 32; ++gg) {
      float r = sigm(xi[gg] + bsh[gg]);
      float z = sigm(xi[32+gg] + bsh[32+gg]);
      float nn = tanhf(xi[64+gg] + r*bsh[64+gg]);
      hs[gg] = (1.f - z)*nn;
    }
  }
  float4 h4[8];
  #pragma unroll
  for (int q = 0; q < 8; ++q) h4[q] = make_float4(hs[4*q], hs[4*q+1], hs[4*q+2], hs[4*q+3]);
  for (int s = 0; s < 2; ++s) {
    const float* xi = XI + (s == 0 ? rid1 : rid2)*96;
    for (int gg = 0; gg < 32; ++gg) {
      float ar = bsh[gg], az = bsh[32+gg], an = bsh[64+gg];
      const float4* wr = (const float4*)&wsh[gg*32];
      const float4* wz = (const float4*)&wsh[(32+gg)*32];
      const float4* wn = (const float4*)&wsh[(64+gg)*32];
      #pragma unroll
      for (int q = 0; q < 8; ++q) {
        float4 hv = h4[q]; float4 w;
        w = wr[q]; ar += hv.x*w.x + hv.y*w.y + hv.z*w.z + hv.w*w.w;
        w = wz[q]; az += hv.x*w.x + hv.y*w.y + hv.z*w.z + hv.w*w.w;
        w = wn[q]; an += hv.x*w.x + hv.y*w.y + hv.z*w.z + hv.w*w.w;
      }
      float r = sigm(xi[gg] + ar);
      float z = sigm(xi[32+gg] + az);
      float nn = tanhf(xi[64+gg] + r*an);
      hs[gg] = (1.f - z)*nn + z*hs[gg];
    }
    #pragma unroll
    for (int q = 0; q < 8; ++q) h4[q] = make_float4(hs[4*q], hs[4*q+1], hs[4*q+2], hs[4*q+3]);
  }
  float* lp = last + (size_t)p*32;
  #pragma unroll
  for (int d = 0; d < 32; ++d) lp[d] = hs[d];
}

// ---------------------------------------------------------------- k_final
__global__ __launch_bounds__(64) void k_final(
    const float* __restrict__ last, const float* __restrict__ r3,
    const int* __restrict__ labels, const float* __restrict__ goutb,
    const float* __restrict__ headb, const float* __restrict__ tailb,
    const float* __restrict__ fcW, const float* __restrict__ fcb,
    float* __restrict__ out) {
  __shared__ float red[64*33];
  __shared__ float gpl[32];
  int b = blockIdx.x, lane = threadIdx.x;
  const float* rl = r3 + labels[b]*32;
  float l32[32];
  {
    const float4* lr = (const float4*)(last + (size_t)(b*64 + lane)*32);
    #pragma unroll
    for (int q = 0; q < 8; ++q) {
      float4 v = lr[q];
      l32[4*q+0]=v.x; l32[4*q+1]=v.y; l32[4*q+2]=v.z; l32[4*q+3]=v.w;
    }
  }
  float s = 0.f;
  #pragma unroll
  for (int d = 0; d < 32; ++d) s += l32[d]*rl[d];
  float mx = s;
  #pragma unroll
  for (int off = 32; off > 0; off >>= 1) mx = fmaxf(mx, __shfl_xor(mx, off));
  float e = __expf(s - mx);
  float den = e;
  #pragma unroll
  for (int off = 32; off > 0; off >>= 1) den += __shfl_xor(den, off);
  float att = e / den;
  #pragma unroll
  for (int d = 0; d < 32; ++d) red[lane*33 + d] = att*l32[d];
  __syncthreads();
  if (lane < 32) {
    float gp = 0.f;
    for (int p2 = 0; p2 < 64; ++p2) gp += red[p2*33 + lane];
    gpl[lane] = gp;
  }
  __syncthreads();
  float acc = 0.f;
  for (int i = lane; i < 352; i += 64) {
    float v;
    if (i < 96)       v = goutb[b*96 + i] * 0.0078125f;
    else if (i < 192) v = headb[b*96 + (i-96)];
    else if (i < 288) v = tailb[b*96 + (i-192)];
    else if (i < 320) v = rl[i-288];
    else              v = gpl[i-320];
    acc += v*fcW[i];
  }
  #pragma unroll
  for (int off = 32; off > 0; off >>= 1) acc += __shfl_xor(acc, off);
  if (lane == 0) out[b] = acc + fcb[0];
}

// ---------------------------------------------------------------- launch
extern "C" void kernel_launch(void* const* d_in, const int* in_sizes, int n_in,
                              void* d_out, int out_size, void* d_ws, size_t ws_size,
                              hipStream_t stream) {
  const float* feat       = (const float*)d_in[0];
  const int*   out_rels   = (const int*)d_in[1];
  const int*   in_rels    = (const int*)d_in[2];
  const int*   r_label_nd = (const int*)d_in[3];
  const int*   src        = (const int*)d_in[4];
  const int*   dst        = (const int*)d_in[5];
  const int*   etype      = (const int*)d_in[6];
  const int*   rel_labels = (const int*)d_in[7];
  const float* rel_emb    = (const float*)d_in[8];
  const float* w2e_W      = (const float*)d_in[9];
  const float* w2e_b      = (const float*)d_in[10];
  const float* W_msg      = (const float*)d_in[11];
  const float* W_self     = (const float*)d_in[12];
  const float* b_gnn      = (const float*)d_in[13];
  const float* W_rel      = (const float*)d_in[14];
  const float* gru_bias   = (const float*)d_in[15];
  const float* Wih_f      = (const float*)d_in[16];
  const float* Whh_f      = (const float*)d_in[17];
  const float* bih_f      = (const float*)d_in[18];
  const float* bhh_f      = (const float*)d_in[19];
  const float* Wih_b      = (const float*)d_in[20];
  const float* Whh_b      = (const float*)d_in[21];
  const float* bih_b      = (const float*)d_in[22];
  const float* bhh_b      = (const float*)d_in[23];
  const float* Wo_W       = (const float*)d_in[24];
  const float* Wo_b       = (const float*)d_in[25];
  const float* pWih       = (const float*)d_in[26];
  const float* pWhh       = (const float*)d_in[27];
  const float* pbih       = (const float*)d_in[28];
  const float* pbhh       = (const float*)d_in[29];
  const float* fcW        = (const float*)d_in[30];
  const float* fcb        = (const float*)d_in[31];
  float* out = (float*)d_out;

  float* p = (float*)d_ws;
  float* R1    = p; p += (size_t)NNODE*192;   // AT (96xN) then AT2 (192xN)
  float* AT    = R1;
  float* AT2   = R1;
  float* GI    = p; p += (size_t)NNODE*576 + 16;
  float* r123  = p; p += 3*NREL*32;
  unsigned short* WT1bt = (unsigned short*)p; p += (576*96)/2;
  unsigned short* WoBt  = (unsigned short*)p; p += (96*192)/2;
  float* bcat  = p; p += 576;
  float* XI    = p; p += NREL*96;
  float* ghid0 = p; p += BB*96;
  float* goutb = p; p += BB*96;
  float* headb = p; p += BB*96;
  float* tailb = p; p += BB*96;
  float* lastb = p; p += (size_t)BB*64*32;

  hipMemsetAsync(goutb, 0, BB*96*sizeof(float), stream);
  k_rel2<<<NREL, 96, 0, stream>>>(rel_emb, W_rel, pWih, pbih, r123, XI);
  k_wt1<<<(576*96+255)/256, 256, 0, stream>>>(Wih_f, Wih_b, bih_f, bih_b, Wo_W,
                                              WT1bt, WoBt, bcat);
  k_gnn3<<<BB, 512, 0, stream>>>(feat, out_rels, in_rels, r_label_nd,
                                 w2e_W, w2e_b, rel_emb, r123, src, dst, etype,
                                 W_msg, W_self, b_gnn, AT, ghid0);
  k_gemm1m<<<512, 256, 0, stream>>>(AT, gru_bias, WT1bt, bcat, GI);
  k_gru<<<256, 576, 0, stream>>>(Whh_f, bhh_f, Whh_b, bhh_b, GI, ghid0, AT2);
  k_gemm2m<<<1024, 384, 0, stream>>>(AT2, WoBt, Wo_b, goutb, headb, tailb);
  k_path<<<256, 128, 0, stream>>>(XI, in_rels, rel_labels, pWhh, pbhh, lastb);
  k_final<<<BB, 64, 0, stream>>>(lastb, r123 + 2*NREL*32, rel_labels,
                                 goutb, headb, tailb, fcW, fcb, out);
}

// Round 17
// 460.688 us; speedup vs baseline: 1.1679x; 1.1519x over previous
//
#include <hip/hip_runtime.h>
#include <math.h>

#define BB 512
#define NT 128
#define NREL 201
#define NNODE (BB*NT)
#define NEDGE (NNODE*16)

typedef float f32x4 __attribute__((ext_vector_type(4)));
typedef __attribute__((ext_vector_type(8))) short bf16x8;

__device__ __forceinline__ float sigm(float x) { return 1.f/(1.f + __expf(-x)); }

__device__ __forceinline__ unsigned short f2bf(float f) {
  unsigned u; __builtin_memcpy(&u, &f, 4);
  unsigned r = u + 0x7fffu + ((u >> 16) & 1u);   // RNE
  return (unsigned short)(r >> 16);
}

// ---------------------------------------------------------------- k_rel2 : per-row rel chain + XI (201 blocks x 96)
__global__ __launch_bounds__(96) void k_rel2(const float* __restrict__ rel_emb,
                                             const float* __restrict__ W_rel,
                                             const float* __restrict__ pWih,
                                             const float* __restrict__ pbih,
                                             float* __restrict__ r123,
                                             float* __restrict__ XI) {
  __shared__ float ra[32], rb[32];
  int r = blockIdx.x, tid = threadIdx.x;
  if (tid < 32) ra[tid] = rel_emb[r*32 + tid];
  __syncthreads();
  if (tid < 32) {
    float s = 0.f;
    #pragma unroll
    for (int d = 0; d < 32; ++d) s += ra[d]*W_rel[d*32 + tid];
    rb[tid] = s; r123[0*NREL*32 + r*32 + tid] = s;
  }
  __syncthreads();
  if (tid < 32) {
    float s = 0.f;
    #pragma unroll
    for (int d = 0; d < 32; ++d) s += rb[d]*W_rel[1024 + d*32 + tid];
    ra[tid] = s; r123[1*NREL*32 + r*32 + tid] = s;
  }
  __syncthreads();
  if (tid < 32) {
    float s = 0.f;
    #pragma unroll
    for (int d = 0; d < 32; ++d) s += ra[d]*W_rel[2048 + d*32 + tid];
    rb[tid] = s; r123[2*NREL*32 + r*32 + tid] = s;
  }
  __syncthreads();
  float s = pbih[tid];
  #pragma unroll
  for (int d = 0; d < 32; ++d) s += rb[d]*pWih[tid*32 + d];
  XI[r*96 + tid] = s;
}

// ---------------------------------------------------------------- k_wt1 : WT1bt[576][96] bf16 ; WoBt[96][192] bf16 ; bcat f32
__global__ __launch_bounds__(256) void k_wt1(const float* __restrict__ Wih_f,
                                             const float* __restrict__ Wih_b,
                                             const float* __restrict__ bih_f,
                                             const float* __restrict__ bih_b,
                                             const float* __restrict__ Wo_W,
                                             unsigned short* __restrict__ WT1bt,
                                             unsigned short* __restrict__ WoBt,
                                             float* __restrict__ bcat) {
  int i = blockIdx.x*256 + threadIdx.x;
  if (i < 576*96) {
    int j = i / 96;
    float v = (j < 288) ? Wih_f[i] : Wih_b[i - 288*96];
    WT1bt[i] = f2bf(v);
  }
  if (i < 96*192) {
    int j = i / 192, k = i - j*192;
    WoBt[i] = f2bf(Wo_W[k*96 + j]);
  }
  if (i < 576) bcat[i] = (i < 288) ? bih_f[i] : bih_b[i-288];
}

// ---------------------------------------------------------------- k_sem
__device__ __forceinline__ void sem_att(const float* __restrict__ rel_emb,
                                        const int rels[8], const float tgt[32],
                                        float out[32]) {
  float dots[8]; float mx = -1e30f;
  #pragma unroll
  for (int k = 0; k < 8; ++k) {
    const float4* er = (const float4*)(rel_emb + rels[k]*32);
    float s = 0.f;
    #pragma unroll
    for (int q = 0; q < 8; ++q) {
      float4 v = er[q];
      s += v.x*tgt[4*q+0] + v.y*tgt[4*q+1] + v.z*tgt[4*q+2] + v.w*tgt[4*q+3];
    }
    dots[k] = s; mx = fmaxf(mx, s);
  }
  float den = 0.f;
  #pragma unroll
  for (int k = 0; k < 8; ++k) { float e = __expf(dots[k]-mx); dots[k] = e; den += e; }
  float inv = 1.f/den;
  #pragma unroll
  for (int d = 0; d < 32; ++d) out[d] = 0.f;
  #pragma unroll
  for (int k = 0; k < 8; ++k) {
    const float4* er = (const float4*)(rel_emb + rels[k]*32);
    float a = dots[k]*inv;
    #pragma unroll
    for (int q = 0; q < 8; ++q) {
      float4 v = er[q];
      out[4*q+0] += a*v.x; out[4*q+1] += a*v.y; out[4*q+2] += a*v.z; out[4*q+3] += a*v.w;
    }
  }
}

__global__ __launch_bounds__(256) void k_sem(
    const float* __restrict__ feat, const int* __restrict__ out_rels,
    const int* __restrict__ in_rels, const int* __restrict__ r_label_node,
    const float* __restrict__ rel_emb, const float* __restrict__ W,
    const float* __restrict__ bias, float* __restrict__ hin) {
  int n = blockIdx.x*256 + threadIdx.x;
  float tgt[32];
  {
    const float4* tr = (const float4*)(rel_emb + r_label_node[n]*32);
    #pragma unroll
    for (int q = 0; q < 8; ++q) {
      float4 v = tr[q];
      tgt[4*q+0]=v.x; tgt[4*q+1]=v.y; tgt[4*q+2]=v.z; tgt[4*q+3]=v.w;
    }
  }
  int ro[8], ri[8];
  #pragma unroll
  for (int k = 0; k < 8; ++k) { ro[k] = out_rels[n*8+k]; ri[k] = in_rels[n*8+k]; }
  float osem[32], isem[32];
  sem_att(rel_emb, ro, tgt, osem);
  sem_att(rel_emb, ri, tgt, isem);
  const float4* fr = (const float4*)(feat + (size_t)n*16);
  float4* ho = (float4*)(hin + (size_t)n*32);
  #pragma unroll
  for (int q = 0; q < 4; ++q) ho[q] = fr[q];
  #pragma unroll
  for (int j = 0; j < 16; ++j) {
    float s = bias[j];
    #pragma unroll
    for (int d = 0; d < 32; ++d) s += osem[d]*W[d*16+j] + isem[d]*W[(32+d)*16+j];
    hin[(size_t)n*32 + 16 + j] = sigm(s);
  }
}

// ---------------------------------------------------------------- k_gnn3 : all 3 layers fused, CSR gather
__global__ __launch_bounds__(512) void k_gnn3(
    const float* __restrict__ hin, const float* __restrict__ rel_emb,
    const float* __restrict__ r123,
    const int* __restrict__ src, const int* __restrict__ dst, const int* __restrict__ etype,
    const float* __restrict__ W_msg, const float* __restrict__ W_self,
    const float* __restrict__ b_gnn,
    float* __restrict__ AT, float* __restrict__ ghid0) {
  __shared__ __align__(16) float hl[NT*36];
  __shared__ __align__(16) float hnew[NT*33];
  __shared__ float rl[NREL*32];
  __shared__ unsigned short eidx[2048];
  __shared__ float scratch[16][32];
  __shared__ int cnt[128], fill[128], scanv[128], rowstart[129];
  int g = blockIdx.x;
  int tid = threadIdx.x;
  int d = tid & 31, grp = tid >> 5;

  for (int i = tid; i < NT*32; i += 512) {
    int row = i >> 5, col = i & 31;
    hl[row*36 + col] = hin[(size_t)(g*NT + row)*32 + col];
  }
  if (tid < 128) { cnt[tid] = 0; fill[tid] = 0; }
  __syncthreads();
  for (int i = tid; i < 2048; i += 512)
    atomicAdd(&cnt[dst[g*2048 + i] - g*NT], 1);
  __syncthreads();
  if (tid < 128) scanv[tid] = cnt[tid];
  __syncthreads();
  #pragma unroll
  for (int off = 1; off < 128; off <<= 1) {
    int v = 0;
    if (tid < 128 && tid >= off) v = scanv[tid - off];
    __syncthreads();
    if (tid < 128) scanv[tid] += v;
    __syncthreads();
  }
  if (tid < 128) { rowstart[tid+1] = scanv[tid]; if (tid == 0) rowstart[0] = 0; }
  __syncthreads();
  for (int i = tid; i < 2048; i += 512) {
    int e = g*2048 + i;
    int dl = dst[e] - g*NT;
    int slot = rowstart[dl] + atomicAdd(&fill[dl], 1);
    eidx[slot] = (unsigned short)(((src[e] - g*NT) << 8) | etype[e]);
  }

  for (int l = 0; l < 3; ++l) {
    const float* rsrc = (l == 0) ? rel_emb : (r123 + (size_t)(l-1)*NREL*32);
    for (int i = tid; i < NREL*32; i += 512) rl[i] = rsrc[i];
    float wm[32], ws[32];
    #pragma unroll
    for (int dd = 0; dd < 32; ++dd) {
      wm[dd] = W_msg[l*1024 + dd*32 + d];
      ws[dd] = W_self[l*1024 + dd*32 + d];
    }
    float bj = b_gnn[l*32 + d];
    __syncthreads();
    for (int k2 = 0; k2 < 8; ++k2) {
      int n = grp + k2*16;
      int e0 = rowstart[n], e1 = rowstart[n+1];
      float acc = 0.f;
      for (int e = e0; e < e1; ++e) {
        int pk = eidx[e];
        acc += hl[(pk >> 8)*36 + d] * rl[(pk & 255)*32 + d];
      }
      scratch[grp][d] = acc;
      float invd = 1.f / (float)((e1 - e0) > 0 ? (e1 - e0) : 1);
      float sa = 0.f, sh = 0.f;
      #pragma unroll
      for (int dd = 0; dd < 32; ++dd) {
        sa += scratch[grp][dd]*wm[dd];
        sh += hl[n*36 + dd]*ws[dd];
      }
      hnew[n*33 + d] = fmaxf(bj + invd*sa + sh, 0.f);
    }
    __syncthreads();
    for (int i = tid; i < NT*32; i += 512) {
      int row = i >> 5, col = i & 31;
      hl[row*36 + col] = hnew[row*33 + col];
    }
    #pragma unroll
    for (int pass = 0; pass < 8; ++pass) {
      int col = (pass << 2) + (tid >> 7);
      int row = tid & 127;
      AT[(size_t)(l*32 + col)*NNODE + g*NT + row] = hnew[row*33 + col];
    }
    {
      float m = -1e30f;
      #pragma unroll
      for (int k2 = 0; k2 < 8; ++k2) m = fmaxf(m, hnew[(grp + k2*16)*33 + d]);
      scratch[grp][d] = m;
    }
    __syncthreads();
    if (tid < 32) {
      float m = -1e30f;
      #pragma unroll
      for (int p2 = 0; p2 < 16; ++p2) m = fmaxf(m, scratch[p2][tid]);
      ghid0[g*96 + l*32 + tid] = m;
    }
    __syncthreads();
  }
}

// ---------------------------------------------------------------- k_gemm1m : MFMA bf16, GI f32 [node][576]
__global__ __launch_bounds__(256) void k_gemm1m(
    const float* __restrict__ AT, const float* __restrict__ gbias,
    const unsigned short* __restrict__ WT1bt, const float* __restrict__ bcat,
    float* __restrict__ GI) {
  __shared__ unsigned short As[128*104];
  int m0 = blockIdx.x * 128;
  int tid = threadIdx.x;
  for (int i = tid; i < 96*32; i += 256) {
    int r = i >> 5, c4 = i & 31;
    float4 v = *(const float4*)&AT[(size_t)r*NNODE + m0 + c4*4];
    float b = gbias[r];
    As[(c4*4+0)*104 + r] = f2bf(fmaxf(v.x+b,0.f));
    As[(c4*4+1)*104 + r] = f2bf(fmaxf(v.y+b,0.f));
    As[(c4*4+2)*104 + r] = f2bf(fmaxf(v.z+b,0.f));
    As[(c4*4+3)*104 + r] = f2bf(fmaxf(v.w+b,0.f));
  }
  __syncthreads();
  int w = tid >> 6, l = tid & 63;
  int lr = l & 15, lh = l >> 4;
  bf16x8 afr[2][3];
  #pragma unroll
  for (int tm = 0; tm < 2; ++tm)
    #pragma unroll
    for (int kc = 0; kc < 3; ++kc)
      afr[tm][kc] = *(const bf16x8*)&As[((w*2+tm)*16 + lr)*104 + kc*32 + lh*8];
  for (int nb = 0; nb < 9; ++nb) {
    int n0 = nb*64;
    #pragma unroll
    for (int tn = 0; tn < 4; ++tn) {
      int col = n0 + tn*16 + lr;
      const unsigned short* bp = WT1bt + (size_t)col*96 + lh*8;
      bf16x8 b0 = *(const bf16x8*)(bp);
      bf16x8 b1 = *(const bf16x8*)(bp + 32);
      bf16x8 b2 = *(const bf16x8*)(bp + 64);
      float bb = bcat[col];
      #pragma unroll
      for (int tm = 0; tm < 2; ++tm) {
        f32x4 acc = {bb, bb, bb, bb};
        acc = __builtin_amdgcn_mfma_f32_16x16x32_bf16(afr[tm][0], b0, acc, 0, 0, 0);
        acc = __builtin_amdgcn_mfma_f32_16x16x32_bf16(afr[tm][1], b1, acc, 0, 0, 0);
        acc = __builtin_amdgcn_mfma_f32_16x16x32_bf16(afr[tm][2], b2, acc, 0, 0, 0);
        int rbase = m0 + (w*2+tm)*16 + lh*4;
        #pragma unroll
        for (int r = 0; r < 4; ++r)
          __builtin_nontemporal_store(acc[r], &GI[(size_t)(rbase + r)*576 + col]);
      }
    }
  }
}

// ---------------------------------------------------------------- k_gru : S=4, 576 thr, part[] reduce (R9 proven, 219us)
#define PIN4(v) asm volatile("" : "+v"(v.x), "+v"(v.y), "+v"(v.z), "+v"(v.w))
#define DOT16(acc, W0,W1,W2,W3, X0,X1,X2,X3) \
  acc += W0.x*X0.x + W0.y*X0.y + W0.z*X0.z + W0.w*X0.w \
       + W1.x*X1.x + W1.y*X1.y + W1.z*X1.z + W1.w*X1.w \
       + W2.x*X2.x + W2.y*X2.y + W2.z*X2.z + W2.w*X2.w \
       + W3.x*X3.x + W3.y*X3.y + W3.z*X3.z + W3.w*X3.w

__global__ __launch_bounds__(576, 1) void k_gru(
    const float* __restrict__ Whh_f, const float* __restrict__ bhh_f,
    const float* __restrict__ Whh_b, const float* __restrict__ bhh_b,
    const float* __restrict__ GI, const float* __restrict__ ghid0,
    float* __restrict__ AT2) {
  __shared__ __align__(16) float h_lds[4][96];
  __shared__ float part[4][288][9];
  int bx = blockIdx.x;                  // 256 blocks = 1/CU
  int dir = bx >> 7;
  int gbase = (bx & 127) * 4;
  int tid = threadIdx.x;
  int c = tid % 96;
  int p = tid / 96;
  bool fin = (tid < 384);
  int s = p;

  const float* Whh = dir ? Whh_b : Whh_f;
  const float4* wr0 = (const float4*)(Whh + (size_t)c*96 + p*16);
  const float4* wr1 = (const float4*)(Whh + (size_t)(96+c)*96 + p*16);
  const float4* wr2 = (const float4*)(Whh + (size_t)(192+c)*96 + p*16);
  float4 wa0=wr0[0], wa1=wr0[1], wa2=wr0[2], wa3=wr0[3];
  float4 wb0=wr1[0], wb1=wr1[1], wb2=wr1[2], wb3=wr1[3];
  float4 wc0=wr2[0], wc1=wr2[1], wc2=wr2[2], wc3=wr2[3];

  float bh0=0.f, bh1=0.f, bh2=0.f;
  float gi0=0.f, gi1=0.f, gi2=0.f;
  if (fin) {
    const float* bhh = dir ? bhh_b : bhh_f;
    bh0 = bhh[c]; bh1 = bhh[96+c]; bh2 = bhh[192+c];
    h_lds[s][c] = ghid0[(gbase+s)*96 + c];
    int pos0 = dir ? 127 : 0;
    const float* g = GI + (size_t)((gbase+s)*128 + pos0)*576 + dir*288;
    gi0 = g[c]; gi1 = g[96+c]; gi2 = g[192+c];
  }
  __syncthreads();
  for (int t = 0; t < 128; ++t) {
    PIN4(wa0); PIN4(wa1); PIN4(wa2); PIN4(wa3);
    PIN4(wb0); PIN4(wb1); PIN4(wb2); PIN4(wb3);
    PIN4(wc0); PIN4(wc1); PIN4(wc2); PIN4(wc3);
    int pos = dir ? (127-t) : t;
    float gn0=0.f, gn1=0.f, gn2=0.f;
    if (fin && t < 127) {
      int posn = dir ? (126-t) : (t+1);
      const float* g = GI + (size_t)((gbase+s)*128 + posn)*576 + dir*288;
      gn0 = g[c]; gn1 = g[96+c]; gn2 = g[192+c];
    }
    #pragma unroll
    for (int s4 = 0; s4 < 4; ++s4) {
      const float4* hh = (const float4*)&h_lds[s4][p*16];
      float4 x0=hh[0], x1=hh[1], x2=hh[2], x3=hh[3];
      float q0=0.f, q1=0.f, q2=0.f;
      DOT16(q0, wa0,wa1,wa2,wa3, x0,x1,x2,x3);
      DOT16(q1, wb0,wb1,wb2,wb3, x0,x1,x2,x3);
      DOT16(q2, wc0,wc1,wc2,wc3, x0,x1,x2,x3);
      part[s4][c][p]     = q0;
      part[s4][96+c][p]  = q1;
      part[s4][192+c][p] = q2;
    }
    __syncthreads();
    if (fin) {
      const float* pr = part[s][c];
      const float* pz = part[s][96+c];
      const float* pn = part[s][192+c];
      float ghr = pr[0]+pr[1]+pr[2]+pr[3]+pr[4]+pr[5] + bh0;
      float ghz = pz[0]+pz[1]+pz[2]+pz[3]+pz[4]+pz[5] + bh1;
      float ghn = pn[0]+pn[1]+pn[2]+pn[3]+pn[4]+pn[5] + bh2;
      float r  = sigm(gi0 + ghr);
      float z  = sigm(gi1 + ghz);
      float nn = tanhf(gi2 + r*ghn);
      float hv = (1.f - z)*nn + z*h_lds[s][c];
      h_lds[s][c] = hv;
      AT2[(size_t)(dir*96 + c)*NNODE + (gbase+s)*128 + pos] = fmaxf(hv, 0.f);
      gi0 = gn0; gi1 = gn1; gi2 = gn2;
    }
    __syncthreads();
  }
}

// ---------------------------------------------------------------- k_gemm2m : MFMA bf16 Wo-GEMM + fused pooling
__global__ __launch_bounds__(384) void k_gemm2m(
    const float* __restrict__ AT2, const unsigned short* __restrict__ WoBt,
    const float* __restrict__ Wob, float* __restrict__ goutb,
    float* __restrict__ headb, float* __restrict__ tailb) {
  __shared__ unsigned short As[64*104];
  int m0 = blockIdx.x * 64;
  int g = m0 >> 7;
  int tid = threadIdx.x;
  int w = tid / 64, l = tid & 63;
  int lr = l & 15, lh = l >> 4;
  int col = w*16 + lr;
  float bb = Wob[col];
  f32x4 acc[4];
  #pragma unroll
  for (int mt = 0; mt < 4; ++mt) acc[mt] = (f32x4){bb, bb, bb, bb};
  for (int kc = 0; kc < 2; ++kc) {
    if (kc) __syncthreads();
    for (int i = tid; i < 1536; i += 384) {
      int r = i >> 4, c4 = i & 15;
      float4 v = *(const float4*)&AT2[(size_t)(kc*96 + r)*NNODE + m0 + c4*4];
      As[(c4*4+0)*104 + r] = f2bf(v.x);
      As[(c4*4+1)*104 + r] = f2bf(v.y);
      As[(c4*4+2)*104 + r] = f2bf(v.z);
      As[(c4*4+3)*104 + r] = f2bf(v.w);
    }
    __syncthreads();
    const unsigned short* bp = WoBt + (size_t)col*192 + kc*96 + lh*8;
    bf16x8 b0 = *(const bf16x8*)(bp);
    bf16x8 b1 = *(const bf16x8*)(bp + 32);
    bf16x8 b2 = *(const bf16x8*)(bp + 64);
    #pragma unroll
    for (int mt = 0; mt < 4; ++mt) {
      const unsigned short* ap = &As[(mt*16 + lr)*104 + lh*8];
      bf16x8 a0 = *(const bf16x8*)(ap);
      bf16x8 a1 = *(const bf16x8*)(ap + 32);
      bf16x8 a2 = *(const bf16x8*)(ap + 64);
      acc[mt] = __builtin_amdgcn_mfma_f32_16x16x32_bf16(a0, b0, acc[mt], 0, 0, 0);
      acc[mt] = __builtin_amdgcn_mfma_f32_16x16x32_bf16(a1, b1, acc[mt], 0, 0, 0);
      acc[mt] = __builtin_amdgcn_mfma_f32_16x16x32_bf16(a2, b2, acc[mt], 0, 0, 0);
    }
  }
  float colsum = 0.f;
  bool hb = ((m0 & 127) == 0) && (lh == 0);
  #pragma unroll
  for (int mt = 0; mt < 4; ++mt) {
    #pragma unroll
    for (int r = 0; r < 4; ++r) {
      float v = fmaxf(acc[mt][r], 0.f);
      colsum += v;
      if (hb && mt == 0) {
        if (r == 0) headb[g*96 + col] = v;
        if (r == 1) tailb[g*96 + col] = v;
      }
    }
  }
  colsum += __shfl_xor(colsum, 16);
  colsum += __shfl_xor(colsum, 32);
  if (lh == 0) atomicAdd(&goutb[g*96 + col], colsum);
}

// ---------------------------------------------------------------- k_path
__global__ __launch_bounds__(128) void k_path(
    const float* __restrict__ XI, const int* __restrict__ in_rels,
    const int* __restrict__ labels, const float* __restrict__ pWhh,
    const float* __restrict__ pbhh, float* __restrict__ last) {
  __shared__ __align__(16) float wsh[96*32];
  __shared__ float bsh[96];
  __shared__ float hbuf[128*33];
  int tid = threadIdx.x;
  for (int i = tid; i < 96*32; i += 128) wsh[i] = pWhh[i];
  if (tid < 96) bsh[tid] = pbhh[tid];
  int p = blockIdx.x*128 + tid;
  int b = p >> 6, pp = p & 63;
  int rid0 = in_rels[b*1024 + (pp >> 3)];
  int rid1 = labels[b];
  int rid2 = in_rels[b*1024 + 8 + (pp & 7)];
  __syncthreads();
  float* hs = &hbuf[tid*33];
  {
    const float* xi = XI + rid0*96;
    #pragma unroll
    for (int gg = 0; gg < 32; ++gg) {
      float r = sigm(xi[gg] + bsh[gg]);
      float z = sigm(xi[32+gg] + bsh[32+gg]);
      float nn = tanhf(xi[64+gg] + r*bsh[64+gg]);
      hs[gg] = (1.f - z)*nn;
    }
  }
  float4 h4[8];
  #pragma unroll
  for (int q = 0; q < 8; ++q) h4[q] = make_float4(hs[4*q], hs[4*q+1], hs[4*q+2], hs[4*q+3]);
  for (int s = 0; s < 2; ++s) {
    const float* xi = XI + (s == 0 ? rid1 : rid2)*96;
    for (int gg = 0; gg < 32; ++gg) {
      float ar = bsh[gg], az = bsh[32+gg], an = bsh[64+gg];
      const float4* wr = (const float4*)&wsh[gg*32];
      const float4* wz = (const float4*)&wsh[(32+gg)*32];
      const float4* wn = (const float4*)&wsh[(64+gg)*32];
      #pragma unroll
      for (int q = 0; q < 8; ++q) {
        float4 hv = h4[q]; float4 w;
        w = wr[q]; ar += hv.x*w.x + hv.y*w.y + hv.z*w.z + hv.w*w.w;
        w = wz[q]; az += hv.x*w.x + hv.y*w.y + hv.z*w.z + hv.w*w.w;
        w = wn[q]; an += hv.x*w.x + hv.y*w.y + hv.z*w.z + hv.w*w.w;
      }
      float r = sigm(xi[gg] + ar);
      float z = sigm(xi[32+gg] + az);
      float nn = tanhf(xi[64+gg] + r*an);
      hs[gg] = (1.f - z)*nn + z*hs[gg];
    }
    #pragma unroll
    for (int q = 0; q < 8; ++q) h4[q] = make_float4(hs[4*q], hs[4*q+1], hs[4*q+2], hs[4*q+3]);
  }
  float* lp = last + (size_t)p*32;
  #pragma unroll
  for (int d = 0; d < 32; ++d) lp[d] = hs[d];
}

// ---------------------------------------------------------------- k_final
__global__ __launch_bounds__(64) void k_final(
    const float* __restrict__ last, const float* __restrict__ r3,
    const int* __restrict__ labels, const float* __restrict__ goutb,
    const float* __restrict__ headb, const float* __restrict__ tailb,
    const float* __restrict__ fcW, const float* __restrict__ fcb,
    float* __restrict__ out) {
  __shared__ float red[64*33];
  __shared__ float gpl[32];
  int b = blockIdx.x, lane = threadIdx.x;
  const float* rl = r3 + labels[b]*32;
  float l32[32];
  {
    const float4* lr = (const float4*)(last + (size_t)(b*64 + lane)*32);
    #pragma unroll
    for (int q = 0; q < 8; ++q) {
      float4 v = lr[q];
      l32[4*q+0]=v.x; l32[4*q+1]=v.y; l32[4*q+2]=v.z; l32[4*q+3]=v.w;
    }
  }
  float s = 0.f;
  #pragma unroll
  for (int d = 0; d < 32; ++d) s += l32[d]*rl[d];
  float mx = s;
  #pragma unroll
  for (int off = 32; off > 0; off >>= 1) mx = fmaxf(mx, __shfl_xor(mx, off));
  float e = __expf(s - mx);
  float den = e;
  #pragma unroll
  for (int off = 32; off > 0; off >>= 1) den += __shfl_xor(den, off);
  float att = e / den;
  #pragma unroll
  for (int d = 0; d < 32; ++d) red[lane*33 + d] = att*l32[d];
  __syncthreads();
  if (lane < 32) {
    float gp = 0.f;
    for (int p2 = 0; p2 < 64; ++p2) gp += red[p2*33 + lane];
    gpl[lane] = gp;
  }
  __syncthreads();
  float acc = 0.f;
  for (int i = lane; i < 352; i += 64) {
    float v;
    if (i < 96)       v = goutb[b*96 + i] * 0.0078125f;
    else if (i < 192) v = headb[b*96 + (i-96)];
    else if (i < 288) v = tailb[b*96 + (i-192)];
    else if (i < 320) v = rl[i-288];
    else              v = gpl[i-320];
    acc += v*fcW[i];
  }
  #pragma unroll
  for (int off = 32; off > 0; off >>= 1) acc += __shfl_xor(acc, off);
  if (lane == 0) out[b] = acc + fcb[0];
}

// ---------------------------------------------------------------- launch
extern "C" void kernel_launch(void* const* d_in, const int* in_sizes, int n_in,
                              void* d_out, int out_size, void* d_ws, size_t ws_size,
                              hipStream_t stream) {
  const float* feat       = (const float*)d_in[0];
  const int*   out_rels   = (const int*)d_in[1];
  const int*   in_rels    = (const int*)d_in[2];
  const int*   r_label_nd = (const int*)d_in[3];
  const int*   src        = (const int*)d_in[4];
  const int*   dst        = (const int*)d_in[5];
  const int*   etype      = (const int*)d_in[6];
  const int*   rel_labels = (const int*)d_in[7];
  const float* rel_emb    = (const float*)d_in[8];
  const float* w2e_W      = (const float*)d_in[9];
  const float* w2e_b      = (const float*)d_in[10];
  const float* W_msg      = (const float*)d_in[11];
  const float* W_self     = (const float*)d_in[12];
  const float* b_gnn      = (const float*)d_in[13];
  const float* W_rel      = (const float*)d_in[14];
  const float* gru_bias   = (const float*)d_in[15];
  const float* Wih_f      = (const float*)d_in[16];
  const float* Whh_f      = (const float*)d_in[17];
  const float* bih_f      = (const float*)d_in[18];
  const float* bhh_f      = (const float*)d_in[19];
  const float* Wih_b      = (const float*)d_in[20];
  const float* Whh_b      = (const float*)d_in[21];
  const float* bih_b      = (const float*)d_in[22];
  const float* bhh_b      = (const float*)d_in[23];
  const float* Wo_W       = (const float*)d_in[24];
  const float* Wo_b       = (const float*)d_in[25];
  const float* pWih       = (const float*)d_in[26];
  const float* pWhh       = (const float*)d_in[27];
  const float* pbih       = (const float*)d_in[28];
  const float* pbhh       = (const float*)d_in[29];
  const float* fcW        = (const float*)d_in[30];
  const float* fcb        = (const float*)d_in[31];
  float* out = (float*)d_out;

  float* p = (float*)d_ws;
  float* hin   = p; p += (size_t)NNODE*32;
  float* R1    = p; p += (size_t)NNODE*192;   // AT (96xN) then AT2 (192xN)
  float* AT    = R1;
  float* AT2   = R1;
  float* GI    = p; p += (size_t)NNODE*576 + 16;
  float* r123  = p; p += 3*NREL*32;
  unsigned short* WT1bt = (unsigned short*)p; p += (576*96)/2;
  unsigned short* WoBt  = (unsigned short*)p; p += (96*192)/2;
  float* bcat  = p; p += 576;
  float* XI    = p; p += NREL*96;
  float* ghid0 = p; p += BB*96;
  float* goutb = p; p += BB*96;
  float* headb = p; p += BB*96;
  float* tailb = p; p += BB*96;
  float* lastb = p; p += (size_t)BB*64*32;

  hipMemsetAsync(goutb, 0, BB*96*sizeof(float), stream);
  k_rel2<<<NREL, 96, 0, stream>>>(rel_emb, W_rel, pWih, pbih, r123, XI);
  k_wt1<<<(576*96+255)/256, 256, 0, stream>>>(Wih_f, Wih_b, bih_f, bih_b, Wo_W,
                                              WT1bt, WoBt, bcat);
  k_sem<<<NNODE/256, 256, 0, stream>>>(feat, out_rels, in_rels, r_label_nd,
                                       rel_emb, w2e_W, w2e_b, hin);
  k_gnn3<<<BB, 512, 0, stream>>>(hin, rel_emb, r123, src, dst, etype,
                                 W_msg, W_self, b_gnn, AT, ghid0);
  k_gemm1m<<<512, 256, 0, stream>>>(AT, gru_bias, WT1bt, bcat, GI);
  k_gru<<<256, 576, 0, stream>>>(Whh_f, bhh_f, Whh_b, bhh_b, GI, ghid0, AT2);
  k_gemm2m<<<1024, 384, 0, stream>>>(AT2, WoBt, Wo_b, goutb, headb, tailb);
  k_path<<<256, 128, 0, stream>>>(XI, in_rels, rel_labels, pWhh, pbhh, lastb);
  k_final<<<BB, 64, 0, stream>>>(lastb, r123 + 2*NREL*32, rel_labels,
                                 goutb, headb, tailb, fcW, fcb, out);
}